// Round 7
// baseline (280.998 us; speedup 1.0000x reference)
//
#include <hip/hip_runtime.h>

#define C_ 32
#define D_ 48
#define H_ 64
#define W_ 128
#define HW_ 8192

using short8 = __attribute__((ext_vector_type(8))) short;
using half8  = __attribute__((ext_vector_type(8))) _Float16;
using half4  = __attribute__((ext_vector_type(4))) _Float16;
using half2v = __attribute__((ext_vector_type(2))) _Float16;
using f32x4  = __attribute__((ext_vector_type(4))) float;

__device__ __forceinline__ const unsigned short* uni_ptr(const unsigned short* p) {
    unsigned long long v = (unsigned long long)p;
    unsigned lo = __builtin_amdgcn_readfirstlane((unsigned)v);
    unsigned hi = __builtin_amdgcn_readfirstlane((unsigned)(v >> 32));
    return (const unsigned short*)(((unsigned long long)hi << 32) | lo);
}

// lane n <- lane n-1 (0 fill): wf_shr1
__device__ __forceinline__ float dpp_shr1z(float v) {
    int r = __builtin_amdgcn_update_dpp(0, __builtin_bit_cast(int, v), 0x138, 0xf, 0xf, true);
    return __builtin_bit_cast(float, r);
}
// lane n <- lane n+1 (0 fill): wf_shl1. With exec=48 lanes, lane47 pulls 0.
__device__ __forceinline__ float dpp_shl1z(float v) {
    int r = __builtin_amdgcn_update_dpp(0, __builtin_bit_cast(int, v), 0x130, 0xf, 0xf, true);
    return __builtin_bit_cast(float, r);
}
// max over lanes 0..47, exec must be 48 lanes; result broadcast via lane 47.
// Builtin update_dpp tree: compiler handles DPP write->read hazards (raw asm chain
// of v_max_f32_dpp without s_nops was numerically WRONG — R1 post-mortem).
__device__ __forceinline__ float wave_max48(float v) {
#define RMAX(ctrl)                                                                              \
    {                                                                                           \
        int t_ = __builtin_amdgcn_update_dpp(__builtin_bit_cast(int, v),                        \
                                             __builtin_bit_cast(int, v), ctrl, 0xf, 0xf, false);\
        v = fmaxf(v, __builtin_bit_cast(float, t_));                                            \
    }
    RMAX(0x111) RMAX(0x112) RMAX(0x114) RMAX(0x118) RMAX(0x142) RMAX(0x143)
#undef RMAX
    int m = __builtin_amdgcn_readlane(__builtin_bit_cast(int, v), 47);
    return __builtin_bit_cast(float, m);
}

__device__ __forceinline__ uint4 pack5(float c0, float c1, float c2, float c3, float c4) {
    float s = fabsf(c0) + fabsf(c1) + fabsf(c2) + fabsf(c3) + fabsf(c4);
    float rn = __builtin_amdgcn_rcpf(fmaxf(s, 1e-12f));
    unsigned h0 = __builtin_bit_cast(unsigned short, (_Float16)(c0 * rn));
    unsigned h1 = __builtin_bit_cast(unsigned short, (_Float16)(c1 * rn));
    unsigned h2 = __builtin_bit_cast(unsigned short, (_Float16)(c2 * rn));
    unsigned h3 = __builtin_bit_cast(unsigned short, (_Float16)(c3 * rn));
    unsigned h4 = __builtin_bit_cast(unsigned short, (_Float16)(c4 * rn));
    return uint4{h0 | (h1 << 16), h2 | (h3 << 16), h4, 0u};
}

// Fused front end:
//  blocks [0,2048):     x[c][d][h][w] fp32 -> xtb[c][h][w][d] f16 (vectorized)
//  blocks [2048,4096):  gprep dirs 0,1 (coalesced): gq entry = 5 fp16 L1-normed weights
//  blocks [4096,4352):  gprep dirs 2,3 via LDS transpose, entries in [c][w*64+h] order
//  blocks [4352,4460):  w_refine[co][ci][tap] -> wt[tap][co][ci] f16
__global__ __launch_bounds__(256) void k_front(const float* __restrict__ x,
                                               const float* __restrict__ g,
                                               const float* __restrict__ wr,
                                               _Float16* __restrict__ xtb,
                                               unsigned short* __restrict__ gq,
                                               _Float16* __restrict__ wt) {
    __shared__ float sbuf[10560];
    const int t = threadIdx.x;
    const int bid = blockIdx.x;
    if (bid < 2048) {
        const int c = bid >> 6, h = bid & 63;
        const float4* xb4 = (const float4*)(x + c * (D_ * HW_) + h * W_);
#pragma unroll
        for (int i = 0; i < 6; ++i) {
            int idx = i * 256 + t;  // 1536 float4 = 48d x 32wq
            int d = idx >> 5, wq = idx & 31;
            float4 v = xb4[d * 2048 + wq];
            sbuf[d * 129 + wq * 4 + 0] = v.x;
            sbuf[d * 129 + wq * 4 + 1] = v.y;
            sbuf[d * 129 + wq * 4 + 2] = v.z;
            sbuf[d * 129 + wq * 4 + 3] = v.w;
        }
        __syncthreads();
        half4* xo4 = (half4*)(xtb + ((c * H_ + h) * W_) * D_);
#pragma unroll
        for (int i = 0; i < 6; ++i) {
            int idx = i * 256 + t;  // 1536 half4 = 128w x 12dq
            int w = idx / 12, dq = idx - w * 12;
            half4 hv;
#pragma unroll
            for (int k = 0; k < 4; ++k) hv[k] = (_Float16)sbuf[(dq * 4 + k) * 129 + w];
            xo4[w * 12 + dq] = hv;
        }
    } else if (bid < 4096) {
        int e = (bid - 2048) * 256 + t;  // 0..524287, dirs 0,1
        int dir = e >> 18;
        int c = (e >> 13) & 31;
        int pos = e & 8191;
        const float* gp = g + ((dir * C_ + c) * 5) * HW_ + pos;
        ((uint4*)gq)[e] = pack5(gp[0], gp[HW_], gp[2 * HW_], gp[3 * HW_], gp[4 * HW_]);
    } else if (bid < 4352) {
        int b = bid - 4096;
        int d2 = b >> 7, c = (b >> 2) & 31, w0 = (b & 3) * 32;
        const float* gp = g + (((d2 + 2) * C_ + c) * 5) * HW_;
#pragma unroll
        for (int k = 0; k < 40; ++k) {
            int j = k * 256 + t;  // 10240 = 5 x 64h x 32w
            int i = j >> 11, r = j & 2047;
            int h = r >> 5, wl = r & 31;
            sbuf[i * 2112 + h * 33 + wl] = gp[i * HW_ + h * W_ + w0 + wl];
        }
        __syncthreads();
        uint4* gqo = (uint4*)gq + ((d2 + 2) * C_ + c) * HW_;
#pragma unroll
        for (int k = 0; k < 8; ++k) {
            int j = k * 256 + t;  // 2048 = 32w x 64h
            int wl = j >> 6, h = j & 63;
            int s = h * 33 + wl;
            gqo[(w0 + wl) * 64 + h] = pack5(sbuf[s], sbuf[2112 + s], sbuf[4224 + s],
                                            sbuf[6336 + s], sbuf[8448 + s]);
        }
    } else {
        int idx = (bid - 4352) * 256 + t;  // 27648
        int ci = idx & 31, co = (idx >> 5) & 31, tap = idx >> 10;
        wt[(tap * 32 + co) * 32 + ci] = (_Float16)wr[(co * 32 + ci) * 27 + tap];
    }
}

// Scan step math — identical to the original, bit-for-bit.
template <bool REV>
__device__ __forceinline__ float scan_step(float prev, _Float16 xv, half8 gh) {
    float mx = wave_max48(prev);
    float dm = dpp_shr1z(prev);
    float dp = dpp_shl1z(prev);
    float a = fmaf((float)gh[0], (float)xv, 0.f);
    a = fmaf((float)gh[1], prev, a);
    a = fmaf((float)gh[2], dm, a);
    a = fmaf((float)gh[3], dp, a);
    a = fmaf((float)gh[4], mx, a);
    return a;
}

// One directional pass, address-gen-free inner loop. Caller guarantees exec =
// lanes 0..47 (lane = d). All accesses are rolling-pointer + COMPILE-TIME offset
// (DS = +-SS constexpr); pointers advance once per 8-step group. Tail (last 15
// steps) fully unrolled with compile-time prefetch guards. R6 accounting showed
// ~78 VALU/step vs ~25 core math — the delta was per-step runtime address
// arithmetic (qq*SS muls + 64-bit adds) + per-step uniform branch; this removes it.
template <int T, int SS, bool REV>
__device__ __forceinline__ void scan_pass(const _Float16* __restrict__ xb,
                                          const unsigned short* __restrict__ gqb,
                                          _Float16* __restrict__ ab) {
    constexpr int PF = 8;
    constexpr int DS = REV ? -SS : SS;   // element step for x/ab streams
    constexpr int DG = REV ? -8 : 8;     // ushort step for g stream
    constexpr int G = (T - 1 - PF) / PF; // full prefetch groups (steps 1..G*PF)
    constexpr int S0 = 1 + G * PF;       // first tail step
    const _Float16* x0 = REV ? xb + (T - 1) * SS : xb;
    _Float16* a0 = REV ? ab + (T - 1) * SS : ab;
    const unsigned short* g0 = REV ? gqb + (T - 1) * 8 : gqb;
    float prev = (float)x0[0];
    {
        float o = prev;
        if (REV) o = fmaxf(o, (float)a0[0]);
        a0[0] = (_Float16)o;
    }
    _Float16 xs[PF], as[PF];
    half8 gs[PF];
#pragma unroll
    for (int i = 0; i < PF; ++i) {
        xs[i] = x0[(1 + i) * DS];
        gs[i] = *(const half8*)(g0 + (1 + i) * DG);
        if (REV) as[i] = a0[(1 + i) * DS];
    }
    const _Float16* xp = x0 + (1 + PF) * DS;
    const unsigned short* gp = g0 + (1 + PF) * DG;
    const _Float16* ap = a0 + (1 + PF) * DS;
    _Float16* sp = a0 + DS;
#pragma unroll 1
    for (int grp = 0; grp < G; ++grp) {
#pragma unroll
        for (int i = 0; i < PF; ++i) {
            _Float16 xv = xs[i];
            half8 gh = gs[i];
            float av = REV ? (float)as[i] : 0.f;
            xs[i] = xp[i * DS];
            gs[i] = *(const half8*)(gp + i * DG);
            if (REV) as[i] = ap[i * DS];
            float a = scan_step<REV>(prev, xv, gh);
            float o = REV ? fmaxf(a, av) : a;
            sp[i * DS] = (_Float16)o;
            prev = a;
        }
        xp += PF * DS;
        gp += PF * DG;
        if (REV) ap += PF * DS;
        sp += PF * DS;
    }
    // Tail: steps S0..T-1 (<= 15), compile-time unrolled; prefetch guards fold.
#pragma unroll
    for (int i = 0; i < 2 * PF - 1; ++i) {
        if (S0 + i < T) {
            const int slot = i & (PF - 1);
            _Float16 xv = xs[slot];
            half8 gh = gs[slot];
            float av = REV ? (float)as[slot] : 0.f;
            if (S0 + i + PF < T) {
                xs[slot] = xp[i * DS];
                gs[slot] = *(const half8*)(gp + i * DG);
                if (REV) as[slot] = ap[i * DS];
            }
            float a = scan_step<REV>(prev, xv, gh);
            float o = REV ? fmaxf(a, av) : a;
            sp[i * DS] = (_Float16)o;
            prev = a;
        }
    }
}

// blocks [0,512): W axis lines; [512,1536): H axis lines. fwd then rev (max-combine).
// (R0 layout — proven best. R2/R3/R4 restructurings all lost.)
__global__ __launch_bounds__(256) void k_scan(const _Float16* __restrict__ xtb,
                                              const unsigned short* __restrict__ gq,
                                              _Float16* __restrict__ agg1,
                                              _Float16* __restrict__ agg2) {
    const int lane = threadIdx.x & 63;
    const int wid = threadIdx.x >> 6;
    if (lane >= 48) return;  // exec = 48 lanes for the whole body
    if (blockIdx.x < 512) {
        const int L = blockIdx.x * 4 + wid;  // 0..2047
        const int c = L >> 6, h = L & 63;
        const int base = ((c * H_ + h) * W_) * D_ + lane;
        const _Float16* xb = xtb + base;
        _Float16* ab = agg1 + base;
        const unsigned short* g0 = uni_ptr(gq + (unsigned)((0 * C_ + c) * HW_ + h * W_) * 8);
        const unsigned short* g1 = uni_ptr(gq + (unsigned)((1 * C_ + c) * HW_ + h * W_) * 8);
        scan_pass<W_, D_, false>(xb, g0, ab);
        __builtin_amdgcn_s_waitcnt(0);
        scan_pass<W_, D_, true>(xb, g1, ab);
    } else {
        const int L = (blockIdx.x - 512) * 4 + wid;  // 0..4095
        const int c = L >> 7, w = L & 127;
        const int base = (c * HW_ + w) * D_ + lane;
        const _Float16* xb = xtb + base;
        _Float16* ab = agg2 + base;
        const unsigned short* g2 = uni_ptr(gq + (unsigned)((2 * C_ + c) * HW_ + w * H_) * 8);
        const unsigned short* g3 = uni_ptr(gq + (unsigned)((3 * C_ + c) * HW_ + w * H_) * 8);
        scan_pass<H_, W_ * D_, false>(xb, g2, ab);
        __builtin_amdgcn_s_waitcnt(0);
        scan_pass<H_, W_ * D_, true>(xb, g3, ab);
    }
}

// blocks [0,1024): max(agg1,agg2) -> BN1 -> ReLU -> y2p[h+1][d+1][w+1][c] f16.
// Single-pass: whole 1h x 8w x 48d x 32c tile staged through one skewed f32 LDS
// buffer with ONE __syncthreads. Per-element math identical & same order.
// blocks [1024,1584): zero the pad cells of y2p (h slabs 0/65, d rows 0/49, w cols 0/129)
__global__ __launch_bounds__(256) void k_prep(const _Float16* __restrict__ agg1,
                                              const _Float16* __restrict__ agg2,
                                              const float* __restrict__ bn1s,
                                              const float* __restrict__ bn1b,
                                              _Float16* __restrict__ y2p) {
    const int t = threadIdx.x;
    if (blockIdx.x >= 1024) {
        int i = (blockIdx.x - 1024) * 256 + t;
        if (i < 143136) {
            unsigned u4i;
            if (i < 52000) {
                int slab = i / 26000, off = i % 26000;
                u4i = slab * 65 * 26000 + off;
            } else if (i < 118560) {
                int j = i - 52000;
                int h = j / 1040 + 1, r = j % 1040;
                int d = (r < 520) ? 0 : 49, off = (r < 520) ? r : r - 520;
                u4i = h * 26000 + d * 520 + off;
            } else {
                int j = i - 118560;
                int h = j / 384 + 1, r = j % 384;
                int d = (r >> 3) + 1, r2 = r & 7;
                int w = (r2 >> 2) ? 129 : 0;
                u4i = h * 26000 + d * 520 + w * 4 + (r2 & 3);
            }
            ((uint4*)y2p)[u4i] = uint4{0u, 0u, 0u, 0u};
        }
        return;
    }
    // LDS tile: L[d*267 + wi*33 + c], d<48, wi<8, c<32.
    __shared__ float L[48 * 267 + 8];
    __shared__ float s_inv[32], s_b[32];
    if (t < 32) {
        s_inv[t] = bn1s[t] * rsqrtf(1.f + 1e-5f);
        s_b[t] = bn1b[t];
    }
    __syncthreads();
    const int h = blockIdx.x >> 4;
    const int w0 = (blockIdx.x & 15) * 8;
    const half4* a14 = (const half4*)agg1;
    const half4* a24 = (const half4*)agg2;
#pragma unroll
    for (int it = 0; it < 12; ++it) {
        int i = it * 256 + t;           // [0,3072)
        int c = i / 96, r = i - c * 96; // c in [0,32)
        int wi = r / 12, dq = r - wi * 12;
        int ao = ((c * H_ + h) * W_ + (w0 + wi)) * 12 + dq;
        half4 u1 = a14[ao];
        half4 u2 = a24[ao];
        float si = s_inv[c], sb = s_b[c];
#pragma unroll
        for (int k = 0; k < 4; ++k) {
            float v = fmaxf((float)u1[k], (float)u2[k]);
            L[(dq * 4 + k) * 267 + wi * 33 + c] = fmaxf(v * si + sb, 0.f);
        }
    }
    __syncthreads();
    half2v* yb2 = (half2v*)y2p;
#pragma unroll
    for (int it = 0; it < 24; ++it) {
        int j = it * 256 + t;  // [0,6144)
        int c2 = j & 15, x2 = j >> 4;
        int wi = x2 & 7, d = x2 >> 3;
        const float* lp = &L[d * 267 + wi * 33 + c2 * 2];
        half2v hv;
        hv[0] = (_Float16)lp[0];
        hv[1] = (_Float16)lp[1];
        yb2[(((h + 1) * 50 + (d + 1)) * 130 + (w0 + wi + 1)) * 16 + c2] = hv;
    }
}

// Conv via MFMA f16. Linear LDS [seg=kh*14+dz][w18][c32] staged with global_load_lds.
// Block: 1h x 16w x 12d out; 3 blocks/CU (48 KB + pad). B ds_reads conflict-free.
__global__ __launch_bounds__(256, 3) void k_conv(const _Float16* __restrict__ y2p,
                                                 const _Float16* __restrict__ wt,
                                                 const float* __restrict__ x,
                                                 const float* __restrict__ bn2s,
                                                 const float* __restrict__ bn2b,
                                                 float* __restrict__ out) {
    __shared__ __align__(16) unsigned short ls[24576];  // 49152 B
    const int t = threadIdx.x;
    const int lane = t & 63, wid = t >> 6;
    const int h = blockIdx.x >> 5;
    const int ow = ((blockIdx.x >> 2) & 7) * 16;
    const int od = (blockIdx.x & 3) * 12;
    // Stage 3024 x 16 B: element i -> lds byte i*16. seg = i/72 (kh,dz), off = i%72 (w,cq).
    {
        const int j0 = wid * 12;
#pragma unroll
        for (int jj = 0; jj < 12; ++jj) {
            int j = j0 + jj;
            int i = j * 64 + lane;
            int seg = i / 72, off = i - seg * 72;
            int kh = seg / 14, dz = seg - kh * 14;
            const _Float16* gp = y2p + (unsigned)(((h + kh) * 50 + od + dz) * 520 + ow * 4 + off) * 8;
            if (i < 3024)
                __builtin_amdgcn_global_load_lds(
                    (const __attribute__((address_space(1))) void*)gp,
                    (__attribute__((address_space(3))) void*)(ls + (unsigned)j * 512), 16, 0, 0);
        }
    }
    __syncthreads();
    const int n = lane & 15, kg = lane >> 4;
    const int dd0 = wid * 3;
    f32x4 acc[3][2] = {};
#pragma unroll
    for (int kh = 0; kh < 3; ++kh)
#pragma unroll
        for (int kd = 0; kd < 3; ++kd)
#pragma unroll
            for (int kw = 0; kw < 3; ++kw) {
                int tap = (kd * 3 + kh) * 3 + kw;
                half8 A0 = *(const half8*)(wt + (tap * 32 + n) * 32 + kg * 8);
                half8 A1 = *(const half8*)(wt + (tap * 32 + 16 + n) * 32 + kg * 8);
                const unsigned short* bp =
                    ls + (kh * 14 + dd0 + kd) * 576 + (n + kw) * 32 + kg * 8;
#pragma unroll
                for (int dd = 0; dd < 3; ++dd) {
                    half8 b = __builtin_bit_cast(half8, *(const short8*)(bp + dd * 576));
                    acc[dd][0] = __builtin_amdgcn_mfma_f32_16x16x32_f16(A0, b, acc[dd][0], 0, 0, 0);
                    acc[dd][1] = __builtin_amdgcn_mfma_f32_16x16x32_f16(A1, b, acc[dd][1], 0, 0, 0);
                }
            }
    const float rs = rsqrtf(1.f + 1e-5f);
#pragma unroll
    for (int ct = 0; ct < 2; ++ct)
#pragma unroll
        for (int r = 0; r < 4; ++r) {
            int co = ct * 16 + kg * 4 + r;
            float sc = bn2s[co] * rs, bi = bn2b[co];
#pragma unroll
            for (int dd = 0; dd < 3; ++dd) {
                int d = od + dd0 + dd;
                int addr = ((co * D_ + d) * H_ + h) * W_ + ow + n;
                float val = acc[dd][ct][r] * sc + bi;
                out[addr] = fmaxf(val + x[addr], 0.f);
            }
        }
}

extern "C" void kernel_launch(void* const* d_in, const int* in_sizes, int n_in,
                              void* d_out, int out_size, void* d_ws, size_t ws_size,
                              hipStream_t stream) {
    const float* x = (const float*)d_in[0];
    const float* g = (const float*)d_in[1];
    const float* wr = (const float*)d_in[2];
    const float* bn1s = (const float*)d_in[3];
    const float* bn1b = (const float*)d_in[4];
    const float* bn2s = (const float*)d_in[5];
    const float* bn2b = (const float*)d_in[6];
    float* out = (float*)d_out;
    char* ws = (char*)d_ws;

    _Float16* xtb = (_Float16*)ws;                       // 25,165,824 B (dead after scans)
    _Float16* y2p = (_Float16*)ws;                       // 27,456,000 B (aliases xtb)
    _Float16* agg1 = (_Float16*)(ws + 33554432);         // 25,165,824 B
    _Float16* agg2 = (_Float16*)(ws + 58720256);         // 25,165,824 B
    unsigned short* gq = (unsigned short*)(ws + 83886080);  // 16,777,216 B
    _Float16* wt = (_Float16*)(ws + 100663296);          // 55,296 B -> total 100,718,592

    k_front<<<4460, 256, 0, stream>>>(x, g, wr, xtb, gq, wt);
    k_scan<<<1536, 256, 0, stream>>>(xtb, gq, agg1, agg2);
    k_prep<<<1584, 256, 0, stream>>>(agg1, agg2, bn1s, bn1b, y2p);
    k_conv<<<2048, 256, 0, stream>>>(y2p, wt, x, bn2s, bn2b, out);
}

// Round 8
// 269.614 us; speedup vs baseline: 1.0422x; 1.0422x over previous
//
#include <hip/hip_runtime.h>

#define C_ 32
#define D_ 48
#define H_ 64
#define W_ 128
#define HW_ 8192

using short8 = __attribute__((ext_vector_type(8))) short;
using half8  = __attribute__((ext_vector_type(8))) _Float16;
using half4  = __attribute__((ext_vector_type(4))) _Float16;
using half2v = __attribute__((ext_vector_type(2))) _Float16;
using f32x4  = __attribute__((ext_vector_type(4))) float;

__device__ __forceinline__ const unsigned short* uni_ptr(const unsigned short* p) {
    unsigned long long v = (unsigned long long)p;
    unsigned lo = __builtin_amdgcn_readfirstlane((unsigned)v);
    unsigned hi = __builtin_amdgcn_readfirstlane((unsigned)(v >> 32));
    return (const unsigned short*)(((unsigned long long)hi << 32) | lo);
}

// lane n <- lane n-1 (0 fill): wf_shr1
__device__ __forceinline__ float dpp_shr1z(float v) {
    int r = __builtin_amdgcn_update_dpp(0, __builtin_bit_cast(int, v), 0x138, 0xf, 0xf, true);
    return __builtin_bit_cast(float, r);
}
// lane n <- lane n+1 (0 fill): wf_shl1. With exec=48 lanes, lane47 pulls 0.
__device__ __forceinline__ float dpp_shl1z(float v) {
    int r = __builtin_amdgcn_update_dpp(0, __builtin_bit_cast(int, v), 0x130, 0xf, 0xf, true);
    return __builtin_bit_cast(float, r);
}
// max over lanes 0..47, exec must be 48 lanes; result broadcast via lane 47.
// Builtin update_dpp tree: compiler handles DPP write->read hazards (raw asm chain
// of v_max_f32_dpp without s_nops was numerically WRONG — R1 post-mortem).
__device__ __forceinline__ float wave_max48(float v) {
#define RMAX(ctrl)                                                                              \
    {                                                                                           \
        int t_ = __builtin_amdgcn_update_dpp(__builtin_bit_cast(int, v),                        \
                                             __builtin_bit_cast(int, v), ctrl, 0xf, 0xf, false);\
        v = fmaxf(v, __builtin_bit_cast(float, t_));                                            \
    }
    RMAX(0x111) RMAX(0x112) RMAX(0x114) RMAX(0x118) RMAX(0x142) RMAX(0x143)
#undef RMAX
    int m = __builtin_amdgcn_readlane(__builtin_bit_cast(int, v), 47);
    return __builtin_bit_cast(float, m);
}

__device__ __forceinline__ uint4 pack5(float c0, float c1, float c2, float c3, float c4) {
    float s = fabsf(c0) + fabsf(c1) + fabsf(c2) + fabsf(c3) + fabsf(c4);
    float rn = __builtin_amdgcn_rcpf(fmaxf(s, 1e-12f));
    unsigned h0 = __builtin_bit_cast(unsigned short, (_Float16)(c0 * rn));
    unsigned h1 = __builtin_bit_cast(unsigned short, (_Float16)(c1 * rn));
    unsigned h2 = __builtin_bit_cast(unsigned short, (_Float16)(c2 * rn));
    unsigned h3 = __builtin_bit_cast(unsigned short, (_Float16)(c3 * rn));
    unsigned h4 = __builtin_bit_cast(unsigned short, (_Float16)(c4 * rn));
    return uint4{h0 | (h1 << 16), h2 | (h3 << 16), h4, 0u};
}

// Fused front end (R8 layout: heavy dirs23 blocks FIRST + split in h-halves;
// sbuf shrunk 10560->6192 floats so the whole kernel runs 6 blocks/CU not 3):
//  blocks [0,512):      gprep dirs 2,3 via LDS transpose, one h-half (32h x 32w) each
//  blocks [512,2560):   x[c][d][h][w] fp32 -> xtb[c][h][w][d] f16 (vectorized)
//  blocks [2560,4608):  gprep dirs 0,1 (coalesced): gq entry = 5 fp16 L1-normed weights
//  blocks [4608,4716):  w_refine[co][ci][tap] -> wt[tap][co][ci] f16
__global__ __launch_bounds__(256) void k_front(const float* __restrict__ x,
                                               const float* __restrict__ g,
                                               const float* __restrict__ wr,
                                               _Float16* __restrict__ xtb,
                                               unsigned short* __restrict__ gq,
                                               _Float16* __restrict__ wt) {
    __shared__ float sbuf[6192];  // 24.8 KB: xtb branch needs 6190, dirs23 half needs 5280
    const int t = threadIdx.x;
    const int bid = blockIdx.x;
    if (bid < 512) {
        int b = bid >> 1;
        int h0 = (bid & 1) * 32;
        int d2 = b >> 7, c = (b >> 2) & 31, w0 = (b & 3) * 32;
        const float* gp = g + (((d2 + 2) * C_ + c) * 5) * HW_;
#pragma unroll
        for (int k = 0; k < 20; ++k) {
            int j = k * 256 + t;  // 5120 = 5 x 32h x 32w
            int i = j >> 10, r = j & 1023;
            int hl = r >> 5, wl = r & 31;
            sbuf[i * 1056 + hl * 33 + wl] = gp[i * HW_ + (h0 + hl) * W_ + w0 + wl];
        }
        __syncthreads();
        uint4* gqo = (uint4*)gq + ((d2 + 2) * C_ + c) * HW_;
#pragma unroll
        for (int k = 0; k < 4; ++k) {
            int j = k * 256 + t;  // 1024 = 32w x 32h
            int wl = j >> 5, hl = j & 31;
            int s = hl * 33 + wl;
            gqo[(w0 + wl) * 64 + h0 + hl] = pack5(sbuf[s], sbuf[1056 + s], sbuf[2112 + s],
                                                  sbuf[3168 + s], sbuf[4224 + s]);
        }
    } else if (bid < 2560) {
        const int b = bid - 512;
        const int c = b >> 6, h = b & 63;
        const float4* xb4 = (const float4*)(x + c * (D_ * HW_) + h * W_);
#pragma unroll
        for (int i = 0; i < 6; ++i) {
            int idx = i * 256 + t;  // 1536 float4 = 48d x 32wq
            int d = idx >> 5, wq = idx & 31;
            float4 v = xb4[d * 2048 + wq];
            sbuf[d * 129 + wq * 4 + 0] = v.x;
            sbuf[d * 129 + wq * 4 + 1] = v.y;
            sbuf[d * 129 + wq * 4 + 2] = v.z;
            sbuf[d * 129 + wq * 4 + 3] = v.w;
        }
        __syncthreads();
        half4* xo4 = (half4*)(xtb + ((c * H_ + h) * W_) * D_);
#pragma unroll
        for (int i = 0; i < 6; ++i) {
            int idx = i * 256 + t;  // 1536 half4 = 128w x 12dq
            int w = idx / 12, dq = idx - w * 12;
            half4 hv;
#pragma unroll
            for (int k = 0; k < 4; ++k) hv[k] = (_Float16)sbuf[(dq * 4 + k) * 129 + w];
            xo4[w * 12 + dq] = hv;
        }
    } else if (bid < 4608) {
        int e = (bid - 2560) * 256 + t;  // 0..524287, dirs 0,1
        int dir = e >> 18;
        int c = (e >> 13) & 31;
        int pos = e & 8191;
        const float* gp = g + ((dir * C_ + c) * 5) * HW_ + pos;
        ((uint4*)gq)[e] = pack5(gp[0], gp[HW_], gp[2 * HW_], gp[3 * HW_], gp[4 * HW_]);
    } else {
        int idx = (bid - 4608) * 256 + t;  // 27648 = 108 blocks x 256
        int ci = idx & 31, co = (idx >> 5) & 31, tap = idx >> 10;
        wt[(tap * 32 + co) * 32 + ci] = (_Float16)wr[(co * 32 + ci) * 27 + tap];
    }
}

// One directional pass. Caller guarantees exec = lanes 0..47 (lane = d).
// xb/ab per-lane element bases; gqb wave-uniform line base (ushorts).
// (R5 form — proven best; fma_mix (R6) and rolling-pointer (R7) were neutral.)
template <int T, int SS, bool REV>
__device__ __forceinline__ void scan_pass(const _Float16* __restrict__ xb,
                                          const unsigned short* __restrict__ gqb,
                                          _Float16* __restrict__ ab) {
    constexpr int PF = 8;
    _Float16 xs[PF], as[PF];
    half8 gs[PF];
    float prev;
    {
        constexpr int q0 = REV ? (T - 1) : 0;
        prev = (float)xb[q0 * SS];
        float o = prev;
        if (REV) o = fmaxf(o, (float)ab[q0 * SS]);
        ab[q0 * SS] = (_Float16)o;
    }
#pragma unroll
    for (int i = 0; i < PF; ++i) {
        int q = REV ? (T - 2 - i) : (1 + i);
        xs[i] = xb[q * SS];
        gs[i] = *(const half8*)(gqb + q * 8);
        if (REV) as[i] = ab[q * SS];
    }
    auto step = [&](int pc, int slot) {
        _Float16 xv = xs[slot];
        half8 gh = gs[slot];
        float av = REV ? (float)as[slot] : 0.f;
        int pn = pc + PF;
        if (pn < T) {
            int qn = REV ? (T - 1 - pn) : pn;
            xs[slot] = xb[qn * SS];
            gs[slot] = *(const half8*)(gqb + qn * 8);
            if (REV) as[slot] = ab[qn * SS];
        }
        float mx = wave_max48(prev);
        float dm = dpp_shr1z(prev);
        float dp = dpp_shl1z(prev);
        float a = fmaf((float)gh[0], (float)xv, 0.f);
        a = fmaf((float)gh[1], prev, a);
        a = fmaf((float)gh[2], dm, a);
        a = fmaf((float)gh[3], dp, a);
        a = fmaf((float)gh[4], mx, a);
        float o = REV ? fmaxf(a, av) : a;
        int qq = REV ? (T - 1 - pc) : pc;
        ab[qq * SS] = (_Float16)o;
        prev = a;
    };
    int p = 1;
#pragma unroll 1
    for (; p + PF <= T; p += PF) {
#pragma unroll
        for (int i = 0; i < PF; ++i) step(p + i, i);
    }
#pragma unroll
    for (int i = 0; i < PF; ++i)
        if (p + i < T) step(p + i, i);
}

// blocks [0,512): W axis lines; [512,1536): H axis lines. fwd then rev (max-combine).
// (R0 layout — proven best. R2/R3/R4 restructurings all lost.)
__global__ __launch_bounds__(256) void k_scan(const _Float16* __restrict__ xtb,
                                              const unsigned short* __restrict__ gq,
                                              _Float16* __restrict__ agg1,
                                              _Float16* __restrict__ agg2) {
    const int lane = threadIdx.x & 63;
    const int wid = threadIdx.x >> 6;
    if (lane >= 48) return;  // exec = 48 lanes for the whole body
    if (blockIdx.x < 512) {
        const int L = blockIdx.x * 4 + wid;  // 0..2047
        const int c = L >> 6, h = L & 63;
        const int base = ((c * H_ + h) * W_) * D_ + lane;
        const _Float16* xb = xtb + base;
        _Float16* ab = agg1 + base;
        const unsigned short* g0 = uni_ptr(gq + (unsigned)((0 * C_ + c) * HW_ + h * W_) * 8);
        const unsigned short* g1 = uni_ptr(gq + (unsigned)((1 * C_ + c) * HW_ + h * W_) * 8);
        scan_pass<W_, D_, false>(xb, g0, ab);
        __builtin_amdgcn_s_waitcnt(0);
        scan_pass<W_, D_, true>(xb, g1, ab);
    } else {
        const int L = (blockIdx.x - 512) * 4 + wid;  // 0..4095
        const int c = L >> 7, w = L & 127;
        const int base = (c * HW_ + w) * D_ + lane;
        const _Float16* xb = xtb + base;
        _Float16* ab = agg2 + base;
        const unsigned short* g2 = uni_ptr(gq + (unsigned)((2 * C_ + c) * HW_ + w * H_) * 8);
        const unsigned short* g3 = uni_ptr(gq + (unsigned)((3 * C_ + c) * HW_ + w * H_) * 8);
        scan_pass<H_, W_ * D_, false>(xb, g2, ab);
        __builtin_amdgcn_s_waitcnt(0);
        scan_pass<H_, W_ * D_, true>(xb, g3, ab);
    }
}

// blocks [0,1024): max(agg1,agg2) -> BN1 -> ReLU -> y2p[h+1][d+1][w+1][c] f16.
// Single-pass: whole 1h x 8w x 48d x 32c tile staged through one skewed f32 LDS
// buffer with ONE __syncthreads. Per-element math identical & same order.
// blocks [1024,1584): zero the pad cells of y2p (h slabs 0/65, d rows 0/49, w cols 0/129)
__global__ __launch_bounds__(256) void k_prep(const _Float16* __restrict__ agg1,
                                              const _Float16* __restrict__ agg2,
                                              const float* __restrict__ bn1s,
                                              const float* __restrict__ bn1b,
                                              _Float16* __restrict__ y2p) {
    const int t = threadIdx.x;
    if (blockIdx.x >= 1024) {
        int i = (blockIdx.x - 1024) * 256 + t;
        if (i < 143136) {
            unsigned u4i;
            if (i < 52000) {
                int slab = i / 26000, off = i % 26000;
                u4i = slab * 65 * 26000 + off;
            } else if (i < 118560) {
                int j = i - 52000;
                int h = j / 1040 + 1, r = j % 1040;
                int d = (r < 520) ? 0 : 49, off = (r < 520) ? r : r - 520;
                u4i = h * 26000 + d * 520 + off;
            } else {
                int j = i - 118560;
                int h = j / 384 + 1, r = j % 384;
                int d = (r >> 3) + 1, r2 = r & 7;
                int w = (r2 >> 2) ? 129 : 0;
                u4i = h * 26000 + d * 520 + w * 4 + (r2 & 3);
            }
            ((uint4*)y2p)[u4i] = uint4{0u, 0u, 0u, 0u};
        }
        return;
    }
    // LDS tile: L[d*267 + wi*33 + c], d<48, wi<8, c<32.
    __shared__ float L[48 * 267 + 8];
    __shared__ float s_inv[32], s_b[32];
    if (t < 32) {
        s_inv[t] = bn1s[t] * rsqrtf(1.f + 1e-5f);
        s_b[t] = bn1b[t];
    }
    __syncthreads();
    const int h = blockIdx.x >> 4;
    const int w0 = (blockIdx.x & 15) * 8;
    const half4* a14 = (const half4*)agg1;
    const half4* a24 = (const half4*)agg2;
#pragma unroll
    for (int it = 0; it < 12; ++it) {
        int i = it * 256 + t;           // [0,3072)
        int c = i / 96, r = i - c * 96; // c in [0,32)
        int wi = r / 12, dq = r - wi * 12;
        int ao = ((c * H_ + h) * W_ + (w0 + wi)) * 12 + dq;
        half4 u1 = a14[ao];
        half4 u2 = a24[ao];
        float si = s_inv[c], sb = s_b[c];
#pragma unroll
        for (int k = 0; k < 4; ++k) {
            float v = fmaxf((float)u1[k], (float)u2[k]);
            L[(dq * 4 + k) * 267 + wi * 33 + c] = fmaxf(v * si + sb, 0.f);
        }
    }
    __syncthreads();
    half2v* yb2 = (half2v*)y2p;
#pragma unroll
    for (int it = 0; it < 24; ++it) {
        int j = it * 256 + t;  // [0,6144)
        int c2 = j & 15, x2 = j >> 4;
        int wi = x2 & 7, d = x2 >> 3;
        const float* lp = &L[d * 267 + wi * 33 + c2 * 2];
        half2v hv;
        hv[0] = (_Float16)lp[0];
        hv[1] = (_Float16)lp[1];
        yb2[(((h + 1) * 50 + (d + 1)) * 130 + (w0 + wi + 1)) * 16 + c2] = hv;
    }
}

// Conv via MFMA f16. Linear LDS [seg=kh*14+dz][w18][c32] staged with global_load_lds.
// Block: 1h x 16w x 12d out; 3 blocks/CU (48 KB + pad). B ds_reads conflict-free.
__global__ __launch_bounds__(256, 3) void k_conv(const _Float16* __restrict__ y2p,
                                                 const _Float16* __restrict__ wt,
                                                 const float* __restrict__ x,
                                                 const float* __restrict__ bn2s,
                                                 const float* __restrict__ bn2b,
                                                 float* __restrict__ out) {
    __shared__ __align__(16) unsigned short ls[24576];  // 49152 B
    const int t = threadIdx.x;
    const int lane = t & 63, wid = t >> 6;
    const int h = blockIdx.x >> 5;
    const int ow = ((blockIdx.x >> 2) & 7) * 16;
    const int od = (blockIdx.x & 3) * 12;
    // Stage 3024 x 16 B: element i -> lds byte i*16. seg = i/72 (kh,dz), off = i%72 (w,cq).
    {
        const int j0 = wid * 12;
#pragma unroll
        for (int jj = 0; jj < 12; ++jj) {
            int j = j0 + jj;
            int i = j * 64 + lane;
            int seg = i / 72, off = i - seg * 72;
            int kh = seg / 14, dz = seg - kh * 14;
            const _Float16* gp = y2p + (unsigned)(((h + kh) * 50 + od + dz) * 520 + ow * 4 + off) * 8;
            if (i < 3024)
                __builtin_amdgcn_global_load_lds(
                    (const __attribute__((address_space(1))) void*)gp,
                    (__attribute__((address_space(3))) void*)(ls + (unsigned)j * 512), 16, 0, 0);
        }
    }
    __syncthreads();
    const int n = lane & 15, kg = lane >> 4;
    const int dd0 = wid * 3;
    f32x4 acc[3][2] = {};
#pragma unroll
    for (int kh = 0; kh < 3; ++kh)
#pragma unroll
        for (int kd = 0; kd < 3; ++kd)
#pragma unroll
            for (int kw = 0; kw < 3; ++kw) {
                int tap = (kd * 3 + kh) * 3 + kw;
                half8 A0 = *(const half8*)(wt + (tap * 32 + n) * 32 + kg * 8);
                half8 A1 = *(const half8*)(wt + (tap * 32 + 16 + n) * 32 + kg * 8);
                const unsigned short* bp =
                    ls + (kh * 14 + dd0 + kd) * 576 + (n + kw) * 32 + kg * 8;
#pragma unroll
                for (int dd = 0; dd < 3; ++dd) {
                    half8 b = __builtin_bit_cast(half8, *(const short8*)(bp + dd * 576));
                    acc[dd][0] = __builtin_amdgcn_mfma_f32_16x16x32_f16(A0, b, acc[dd][0], 0, 0, 0);
                    acc[dd][1] = __builtin_amdgcn_mfma_f32_16x16x32_f16(A1, b, acc[dd][1], 0, 0, 0);
                }
            }
    const float rs = rsqrtf(1.f + 1e-5f);
#pragma unroll
    for (int ct = 0; ct < 2; ++ct)
#pragma unroll
        for (int r = 0; r < 4; ++r) {
            int co = ct * 16 + kg * 4 + r;
            float sc = bn2s[co] * rs, bi = bn2b[co];
#pragma unroll
            for (int dd = 0; dd < 3; ++dd) {
                int d = od + dd0 + dd;
                int addr = ((co * D_ + d) * H_ + h) * W_ + ow + n;
                float val = acc[dd][ct][r] * sc + bi;
                out[addr] = fmaxf(val + x[addr], 0.f);
            }
        }
}

extern "C" void kernel_launch(void* const* d_in, const int* in_sizes, int n_in,
                              void* d_out, int out_size, void* d_ws, size_t ws_size,
                              hipStream_t stream) {
    const float* x = (const float*)d_in[0];
    const float* g = (const float*)d_in[1];
    const float* wr = (const float*)d_in[2];
    const float* bn1s = (const float*)d_in[3];
    const float* bn1b = (const float*)d_in[4];
    const float* bn2s = (const float*)d_in[5];
    const float* bn2b = (const float*)d_in[6];
    float* out = (float*)d_out;
    char* ws = (char*)d_ws;

    _Float16* xtb = (_Float16*)ws;                       // 25,165,824 B (dead after scans)
    _Float16* y2p = (_Float16*)ws;                       // 27,456,000 B (aliases xtb)
    _Float16* agg1 = (_Float16*)(ws + 33554432);         // 25,165,824 B
    _Float16* agg2 = (_Float16*)(ws + 58720256);         // 25,165,824 B
    unsigned short* gq = (unsigned short*)(ws + 83886080);  // 16,777,216 B
    _Float16* wt = (_Float16*)(ws + 100663296);          // 55,296 B -> total 100,718,592

    k_front<<<4716, 256, 0, stream>>>(x, g, wr, xtb, gq, wt);
    k_scan<<<1536, 256, 0, stream>>>(xtb, gq, agg1, agg2);
    k_prep<<<1584, 256, 0, stream>>>(agg1, agg2, bn1s, bn1b, y2p);
    k_conv<<<2048, 256, 0, stream>>>(y2p, wt, x, bn2s, bn2b, out);
}